// Round 2
// baseline (2662.123 us; speedup 1.0000x reference)
//
#include <hip/hip_runtime.h>
#include <cstdint>

#define TT 24

static __device__ __forceinline__ float fsig(float x){ return 1.0f/(1.0f + __expf(-x)); }
static __device__ __forceinline__ float ftanh(float x){
  float a = fabsf(x);
  float e = __expf(-2.0f*a);
  float t = (1.0f - e)/(1.0f + e);
  return copysignf(t, x);
}
static __device__ __forceinline__ float lrelu(float x){ return x > 0.f ? x : 0.2f*x; }

// ---------------- prep: weight rearrangement ----------------
// W0g/Wih1g/Whh1g[k*256 + jp*4 + q] = w[(q*64+jp)*64 + k]   (gate-interleaved, K-major)
// linwT[k*128 + ch] = lin_w[ch*72 + k]
// cE[h] = sum_c lin_edge_w[h*32+c] * att_edge[h*32+c]
__global__ void kPrep(const float* __restrict__ w_hh0, const float* __restrict__ w_ih1,
                      const float* __restrict__ w_hh1, const float* __restrict__ lin_w,
                      const float* __restrict__ lin_edge_w, const float* __restrict__ att_edge,
                      float* __restrict__ W0g, float* __restrict__ Wih1g, float* __restrict__ Whh1g,
                      float* __restrict__ linwT, float* __restrict__ cE)
{
  int gid = blockIdx.x*256 + threadIdx.x;
  if (gid < 16384){
    int q = gid & 3, jp = (gid>>2)&63, k = gid>>8;
    int src = (q*64+jp)*64 + k;
    W0g[gid]  = w_hh0[src];
    Wih1g[gid]= w_ih1[src];
    Whh1g[gid]= w_hh1[src];
  }
  int g2 = gid - 16384;
  if (g2 >= 0 && g2 < 72*128){
    int k = g2 >> 7, ch = g2 & 127;
    linwT[g2] = lin_w[ch*72 + k];
  }
  if (gid >= 25600 && gid < 25604){
    int h = gid - 25600;
    float s = 0.f;
    for (int c=0;c<32;c++) s += lin_edge_w[h*32+c]*att_edge[h*32+c];
    cE[h] = s;
  }
}

// ---------------- LSTM layer 0 ----------------
__global__ __launch_bounds__(256,2) void kA(const float* __restrict__ x,
      const float* __restrict__ W0g, const float* __restrict__ w_ih0,
      const float* __restrict__ b_ih0, const float* __restrict__ b_hh0,
      float* __restrict__ h1seq, int nodeBase, int cbBlocks, int N)
{
  __shared__ float sW[16384];
  __shared__ float sH[64*36];
  __shared__ float sX[32*32];
  const int tid = threadIdx.x;
  const int jp = tid & 63;
  const int m0 = (tid >> 6) * 8;
  const int blk = blockIdx.x;
  const int nb = nodeBase + blk*32;

  for (int i = tid*4; i < 16384; i += 1024)
    *(float4*)&sW[i] = *(const float4*)&W0g[i];
  {
    int r = tid >> 3, c = (tid & 7)*4;
    int n = nb + r;
    float4 v = {0.f,0.f,0.f,0.f};
    if (n < N) v = *(const float4*)&x[(size_t)n*32 + c];
    *(float4*)&sX[r*32 + c] = v;
  }
  for (int i = tid; i < 64*36; i += 256) sH[i] = 0.f;

  float wih[4], bg[4];
  #pragma unroll
  for (int q=0;q<4;q++){ wih[q] = w_ih0[q*64+jp]; bg[q] = b_ih0[q*64+jp] + b_hh0[q*64+jp]; }
  float cst[8];
  #pragma unroll
  for (int m=0;m<8;m++) cst[m]=0.f;
  __syncthreads();

  for (int t=0;t<TT;t++){
    float acc[8][4];
    #pragma unroll
    for (int m=0;m<8;m++){
      float xv = sX[(m0+m)*32 + 8 + t];
      #pragma unroll
      for (int q=0;q<4;q++) acc[m][q] = xv*wih[q] + bg[q];
    }
    #pragma unroll 4
    for (int k=0;k<64;k++){
      float4 w4 = *(const float4*)&sW[(k<<8) + (jp<<2)];
      float4 hA = *(const float4*)&sH[k*36 + m0];
      float4 hB = *(const float4*)&sH[k*36 + m0 + 4];
      float hv[8] = {hA.x,hA.y,hA.z,hA.w,hB.x,hB.y,hB.z,hB.w};
      #pragma unroll
      for (int m=0;m<8;m++){
        acc[m][0] += hv[m]*w4.x;
        acc[m][1] += hv[m]*w4.y;
        acc[m][2] += hv[m]*w4.z;
        acc[m][3] += hv[m]*w4.w;
      }
    }
    __syncthreads();
    {
      float hn[8];
      #pragma unroll
      for (int m=0;m<8;m++){
        float ig = fsig(acc[m][0]), fg = fsig(acc[m][1]);
        float gg = ftanh(acc[m][2]), og = fsig(acc[m][3]);
        cst[m] = fg*cst[m] + ig*gg;
        hn[m] = og*ftanh(cst[m]);
      }
      float4 wa = {hn[0],hn[1],hn[2],hn[3]};
      float4 wb = {hn[4],hn[5],hn[6],hn[7]};
      *(float4*)&sH[jp*36 + m0]     = wa;
      *(float4*)&sH[jp*36 + m0 + 4] = wb;
    }
    __syncthreads();
    {
      int k = tid >> 2, mm = (tid & 3)*8;
      float4 a = *(const float4*)&sH[k*36 + mm];
      float4 b = *(const float4*)&sH[k*36 + mm + 4];
      size_t base = ((size_t)t*cbBlocks + blk)*2048 + (size_t)k*32 + mm;
      *(float4*)&h1seq[base]   = a;
      *(float4*)&h1seq[base+4] = b;
    }
  }
}

// ---------------- LSTM layer 1 ----------------
__global__ __launch_bounds__(256,2) void kB(const float* __restrict__ Wih1g,
      const float* __restrict__ Whh1g, const float* __restrict__ b_ih1, const float* __restrict__ b_hh1,
      const float* __restrict__ h1seq, float* __restrict__ h2last,
      int nodeBase, int cbBlocks, int N)
{
  __shared__ float sW[16384];
  __shared__ float sHin[2048];
  __shared__ float sH[2048];
  const int tid = threadIdx.x;
  const int jp = tid & 63;
  const int m0 = (tid >> 6) * 8;
  const int blk = blockIdx.x;
  const int nb = nodeBase + blk*32;

  for (int i = tid*4; i < 16384; i += 1024)
    *(float4*)&sW[i] = *(const float4*)&Wih1g[i];
  for (int i = tid; i < 2048; i += 256) sH[i] = 0.f;

  float bg[4];
  #pragma unroll
  for (int q=0;q<4;q++) bg[q] = b_ih1[q*64+jp] + b_hh1[q*64+jp];
  float cst[8];
  #pragma unroll
  for (int m=0;m<8;m++) cst[m]=0.f;
  __syncthreads();

  for (int t=0;t<TT;t++){
    {
      size_t base = ((size_t)t*cbBlocks + blk)*2048 + (size_t)tid*8;
      float4 a = *(const float4*)&h1seq[base];
      float4 b = *(const float4*)&h1seq[base+4];
      *(float4*)&sHin[tid*8]   = a;
      *(float4*)&sHin[tid*8+4] = b;
    }
    __syncthreads();
    float acc[8][4];
    #pragma unroll
    for (int m=0;m<8;m++){
      #pragma unroll
      for (int q=0;q<4;q++) acc[m][q] = bg[q];
    }
    #pragma unroll 4
    for (int k=0;k<64;k++){
      float4 w4 = *(const float4*)&sW[(k<<8) + (jp<<2)];
      float4 hA = *(const float4*)&sHin[k*32 + m0];
      float4 hB = *(const float4*)&sHin[k*32 + m0 + 4];
      float hv[8] = {hA.x,hA.y,hA.z,hA.w,hB.x,hB.y,hB.z,hB.w};
      #pragma unroll
      for (int m=0;m<8;m++){
        acc[m][0] += hv[m]*w4.x;
        acc[m][1] += hv[m]*w4.y;
        acc[m][2] += hv[m]*w4.z;
        acc[m][3] += hv[m]*w4.w;
      }
    }
    #pragma unroll 4
    for (int k=0;k<64;k++){
      float4 w4 = *(const float4*)&Whh1g[(k<<8) + (jp<<2)];
      int pb = (m0 + 8*(k&3)) & 31;
      float4 hA = *(const float4*)&sH[k*32 + pb];
      float4 hB = *(const float4*)&sH[k*32 + pb + 4];
      float hv[8] = {hA.x,hA.y,hA.z,hA.w,hB.x,hB.y,hB.z,hB.w};
      #pragma unroll
      for (int m=0;m<8;m++){
        acc[m][0] += hv[m]*w4.x;
        acc[m][1] += hv[m]*w4.y;
        acc[m][2] += hv[m]*w4.z;
        acc[m][3] += hv[m]*w4.w;
      }
    }
    __syncthreads();
    {
      float hn[8];
      #pragma unroll
      for (int m=0;m<8;m++){
        float ig = fsig(acc[m][0]), fg = fsig(acc[m][1]);
        float gg = ftanh(acc[m][2]), og = fsig(acc[m][3]);
        cst[m] = fg*cst[m] + ig*gg;
        hn[m] = og*ftanh(cst[m]);
      }
      int pb = (m0 + 8*(jp&3)) & 31;
      float4 wa = {hn[0],hn[1],hn[2],hn[3]};
      float4 wb = {hn[4],hn[5],hn[6],hn[7]};
      *(float4*)&sH[jp*32 + pb]     = wa;
      *(float4*)&sH[jp*32 + pb + 4] = wb;
      if (t == TT-1){
        #pragma unroll
        for (int m=0;m<8;m++){
          int n = nb + m0 + m;
          if (n < N) h2last[(size_t)n*64 + jp] = hn[m];
        }
      }
    }
    __syncthreads();
  }
}

// ---------------- GAT linear + attention coefficients ----------------
__global__ __launch_bounds__(256) void kXL(const float* __restrict__ h2last, const float* __restrict__ x,
    const float* __restrict__ linwT, const float* __restrict__ att_src, const float* __restrict__ att_dst,
    float* __restrict__ xl, float* __restrict__ a_src, float* __restrict__ a_dst, int N)
{
  __shared__ float sLW[72*128];
  __shared__ float sC[16*72];
  const int tid = threadIdx.x;
  const int nb0 = blockIdx.x * 16;
  for (int i = tid*4; i < 9216; i += 1024)
    *(float4*)&sLW[i] = *(const float4*)&linwT[i];
  for (int i = tid; i < 16*64; i += 256){
    int m = i >> 6, k = i & 63; int n = nb0 + m;
    sC[m*72 + k] = (n < N) ? h2last[(size_t)n*64 + k] : 0.f;
  }
  if (tid < 128){
    int m = tid >> 3, j = tid & 7; int n = nb0 + m;
    sC[m*72 + 64 + j] = (n < N) ? x[(size_t)n*32 + j] : 0.f;
  }
  __syncthreads();
  const int ch = tid & 127, half = tid >> 7;
  float acc[8];
  #pragma unroll
  for (int m=0;m<8;m++) acc[m]=0.f;
  for (int k=0;k<72;k++){
    float w = sLW[k*128 + ch];
    #pragma unroll
    for (int m=0;m<8;m++) acc[m] += w * sC[(half*8+m)*72 + k];
  }
  float aS = att_src[ch], aD = att_dst[ch];
  int h = ch >> 5;
  #pragma unroll
  for (int m=0;m<8;m++){
    int n = nb0 + half*8 + m;
    float v = acc[m];
    float ps = v*aS, pd = v*aD;
    #pragma unroll
    for (int d=1; d<32; d<<=1){ ps += __shfl_xor(ps, d); pd += __shfl_xor(pd, d); }
    if (n < N){
      xl[(size_t)n*128 + ch] = v;
      if ((ch & 31) == 0){ a_src[n*4 + h] = ps; a_dst[n*4 + h] = pd; }
    }
  }
}

// ---------------- edge_attr mean ----------------
__global__ void kEa(const float* __restrict__ ea, float* __restrict__ acc, int E){
  int gid = blockIdx.x*blockDim.x + threadIdx.x;
  float s = 0.f;
  for (int i = gid; i < E; i += gridDim.x*blockDim.x) s += ea[i];
  #pragma unroll
  for (int d=1; d<64; d<<=1) s += __shfl_xor(s, d);
  if ((threadIdx.x & 63) == 0) atomicAdd(acc, s);
}

// ---------------- CSR build (edge_index is int32 per harness spec) ----------------
__global__ void kDeg(const int* __restrict__ dst, int* __restrict__ deg, int E, int N){
  int e = blockIdx.x*256 + threadIdx.x;
  if (e < E){
    unsigned d = (unsigned)dst[e];
    if (d < (unsigned)N) atomicAdd(&deg[d], 1);
  }
}

__global__ __launch_bounds__(1024) void kScan(const int* __restrict__ deg, int* __restrict__ ptrA,
                                              int* __restrict__ cursor, int N){
  __shared__ int sWS[16];
  __shared__ int sWO[16];
  const int tid = threadIdx.x;
  const int C = (N + 1 + 1023) / 1024;
  const int i0 = tid * C;
  int local = 0;
  for (int i = i0; i < i0 + C && i < N; i++) local += deg[i];
  int lane = tid & 63, wv = tid >> 6;
  int v = local;
  #pragma unroll
  for (int d=1; d<64; d<<=1){ int u = __shfl_up(v, d); if (lane >= d) v += u; }
  if (lane == 63) sWS[wv] = v;
  __syncthreads();
  if (tid < 16){
    int s = sWS[tid];
    int vv = s;
    #pragma unroll
    for (int d=1; d<16; d<<=1){ int u = __shfl_up(vv, d); if (tid >= d) vv += u; }
    sWO[tid] = vv - s;
  }
  __syncthreads();
  int run = sWO[wv] + (v - local);
  for (int i = i0; i < i0 + C; i++){
    if (i <= N){
      ptrA[i] = run;
      if (i < N){ cursor[i] = run; run += deg[i]; }
    }
  }
}

__global__ void kFill(const int* __restrict__ dst, int* __restrict__ cursor,
                      int* __restrict__ csr, int E, int N){
  int e = blockIdx.x*256 + threadIdx.x;
  if (e < E){
    unsigned d = (unsigned)dst[e];
    if (d < (unsigned)N){ int p = atomicAdd(&cursor[d], 1); csr[p] = e; }
  }
}

// ---------------- GAT aggregation + elu + fc + relu ----------------
__global__ __launch_bounds__(256) void kAgg(const float* __restrict__ xl, const float* __restrict__ a_src,
    const float* __restrict__ a_dst, const int* __restrict__ esrc, const float* __restrict__ eattr,
    const int* __restrict__ ptrA, const int* __restrict__ csr, const float* __restrict__ cE,
    const float* __restrict__ eacc, const float* __restrict__ gat_bias, const float* __restrict__ fc_w,
    const float* __restrict__ fc_b, float* __restrict__ out, int N, int E)
{
  const int n = blockIdx.x*4 + (threadIdx.x >> 6);
  const int lane = threadIdx.x & 63;
  if (n >= N) return;
  float4 cEv = *(const float4*)cE;
  float eam = eacc[0] / (float)E;
  float4 ad  = *(const float4*)&a_dst[n*4];
  float4 asn = *(const float4*)&a_src[n*4];
  float sl0 = lrelu(asn.x + ad.x + eam*cEv.x);
  float sl1 = lrelu(asn.y + ad.y + eam*cEv.y);
  float sl2 = lrelu(asn.z + ad.z + eam*cEv.z);
  float sl3 = lrelu(asn.w + ad.w + eam*cEv.w);
  float mx0=sl0, mx1=sl1, mx2=sl2, mx3=sl3;
  const int p0 = ptrA[n], p1 = ptrA[n+1];
  for (int i = p0 + lane; i < p1; i += 64){
    int e = csr[i];
    int s = esrc[e];
    float ev = eattr[e];
    float4 av = *(const float4*)&a_src[s*4];
    mx0 = fmaxf(mx0, lrelu(av.x + ad.x + ev*cEv.x));
    mx1 = fmaxf(mx1, lrelu(av.y + ad.y + ev*cEv.y));
    mx2 = fmaxf(mx2, lrelu(av.z + ad.z + ev*cEv.z));
    mx3 = fmaxf(mx3, lrelu(av.w + ad.w + ev*cEv.w));
  }
  #pragma unroll
  for (int d=1; d<64; d<<=1){
    mx0 = fmaxf(mx0, __shfl_xor(mx0,d));
    mx1 = fmaxf(mx1, __shfl_xor(mx1,d));
    mx2 = fmaxf(mx2, __shfl_xor(mx2,d));
    mx3 = fmaxf(mx3, __shfl_xor(mx3,d));
  }
  const int ch0 = lane, ch1 = lane + 64;
  const int h0 = lane >> 5;
  float adh0 = h0 ? ad.y : ad.x,  adh1 = h0 ? ad.w : ad.z;
  float ceh0 = h0 ? cEv.y : cEv.x, ceh1 = h0 ? cEv.w : cEv.z;
  float mxh0 = h0 ? mx1 : mx0,    mxh1 = h0 ? mx3 : mx2;
  float slh0 = h0 ? sl1 : sl0,    slh1 = h0 ? sl3 : sl2;
  float pse0 = __expf(slh0 - mxh0), pse1 = __expf(slh1 - mxh1);
  float den0 = pse0, den1 = pse1;
  float acc0 = pse0 * xl[(size_t)n*128 + ch0];
  float acc1 = pse1 * xl[(size_t)n*128 + ch1];
  for (int i = p0; i < p1; i++){
    int e = csr[i];
    int s = esrc[e];
    float ev = eattr[e];
    float4 av = *(const float4*)&a_src[s*4];
    float avh0 = h0 ? av.y : av.x;
    float avh1 = h0 ? av.w : av.z;
    float pp0 = __expf(lrelu(avh0 + adh0 + ev*ceh0) - mxh0);
    float pp1 = __expf(lrelu(avh1 + adh1 + ev*ceh1) - mxh1);
    den0 += pp0; den1 += pp1;
    acc0 += pp0 * xl[(size_t)s*128 + ch0];
    acc1 += pp1 * xl[(size_t)s*128 + ch1];
  }
  float v0 = acc0/(den0 + 1e-16f) + gat_bias[ch0];
  float v1 = acc1/(den1 + 1e-16f) + gat_bias[ch1];
  v0 = v0 > 0.f ? v0 : __expf(v0) - 1.f;
  v1 = v1 > 0.f ? v1 : __expf(v1) - 1.f;
  #pragma unroll
  for (int o=0;o<4;o++){
    float p = fc_w[o*128 + ch0]*v0 + fc_w[o*128 + ch1]*v1;
    #pragma unroll
    for (int d=1; d<64; d<<=1) p += __shfl_xor(p, d);
    if (lane == 0) out[(size_t)n*4 + o] = fmaxf(p + fc_b[o], 0.f);
  }
}

static inline long long llmin(long long a, long long b){ return a < b ? a : b; }

extern "C" void kernel_launch(void* const* d_in, const int* in_sizes, int n_in,
                              void* d_out, int out_size, void* d_ws, size_t ws_size,
                              hipStream_t stream)
{
  (void)n_in; (void)out_size;
  const float* x          = (const float*)d_in[0];
  const int*   eidx       = (const int*)d_in[1];   // int32 per harness spec
  const float* eattr      = (const float*)d_in[2];
  const float* w_ih0      = (const float*)d_in[3];
  const float* w_hh0      = (const float*)d_in[4];
  const float* b_ih0      = (const float*)d_in[5];
  const float* b_hh0      = (const float*)d_in[6];
  const float* w_ih1      = (const float*)d_in[7];
  const float* w_hh1      = (const float*)d_in[8];
  const float* b_ih1      = (const float*)d_in[9];
  const float* b_hh1      = (const float*)d_in[10];
  const float* lin_w      = (const float*)d_in[11];
  const float* lin_edge_w = (const float*)d_in[12];
  const float* att_src    = (const float*)d_in[13];
  const float* att_dst    = (const float*)d_in[14];
  const float* att_edge   = (const float*)d_in[15];
  const float* gat_bias   = (const float*)d_in[16];
  const float* fc_w       = (const float*)d_in[17];
  const float* fc_b       = (const float*)d_in[18];
  float* out = (float*)d_out;

  const int N = in_sizes[0] / 32;
  const int E = in_sizes[1] / 2;
  const int nB = (N + 31) / 32;
  const int* esrc = eidx;
  const int* edst = eidx + E;

  float* ws = (float*)d_ws;
  size_t o = 0;
  float* W0g    = ws + o; o += 16384;
  float* Wih1g  = ws + o; o += 16384;
  float* Whh1g  = ws + o; o += 16384;
  float* linwT  = ws + o; o += 72*128;
  float* cE     = ws + o; o += 4;
  float* eacc   = ws + o; o += 4;
  float* h2last = ws + o; o += (size_t)N*64;
  float* xl     = ws + o; o += (size_t)N*128;
  float* a_src  = ws + o; o += (size_t)N*4;
  float* a_dst  = ws + o; o += (size_t)N*4;
  int* deg      = (int*)(ws + o); o += (size_t)N;
  int* ptrA     = (int*)(ws + o); o += (size_t)N + 1;
  int* cursor   = (int*)(ws + o); o += (size_t)N;
  int* csr      = (int*)(ws + o); o += (size_t)E;
  o = (o + 3) & ~(size_t)3;
  float* h1seq  = ws + o;

  const size_t availF = ws_size / 4;
  const size_t perBlk = (size_t)TT * 2048;
  long long rem = (long long)availF - (long long)o;
  int CH = (int)llmin((long long)nB, rem > 0 ? rem / (long long)perBlk : 1);
  if (CH < 1) CH = 1;

  hipMemsetAsync(deg, 0, (size_t)N*4, stream);
  hipMemsetAsync(eacc, 0, 4, stream);
  kPrep<<<101, 256, 0, stream>>>(w_hh0, w_ih1, w_hh1, lin_w, lin_edge_w, att_edge,
                                 W0g, Wih1g, Whh1g, linwT, cE);
  kEa<<<512, 256, 0, stream>>>(eattr, eacc, E);
  kDeg<<<(E+255)/256, 256, 0, stream>>>(edst, deg, E, N);
  kScan<<<1, 1024, 0, stream>>>(deg, ptrA, cursor, N);
  kFill<<<(E+255)/256, 256, 0, stream>>>(edst, cursor, csr, E, N);

  for (int c0 = 0; c0 < nB; c0 += CH){
    int cb = nB - c0 < CH ? nB - c0 : CH;
    kA<<<cb, 256, 0, stream>>>(x, W0g, w_ih0, b_ih0, b_hh0, h1seq, c0*32, cb, N);
    kB<<<cb, 256, 0, stream>>>(Wih1g, Whh1g, b_ih1, b_hh1, h1seq, h2last, c0*32, cb, N);
  }

  kXL<<<(N+15)/16, 256, 0, stream>>>(h2last, x, linwT, att_src, att_dst, xl, a_src, a_dst, N);
  kAgg<<<(N+3)/4, 256, 0, stream>>>(xl, a_src, a_dst, esrc, eattr, ptrA, csr, cE, eacc,
                                    gat_bias, fc_w, fc_b, out, N, E);
}